// Round 1
// baseline (793.216 us; speedup 1.0000x reference)
//
#include <hip/hip_runtime.h>

#define BS 256
#define NFEAT 121

// Feature offsets: f_l starts at column l*l, width 2l+1. Total 121.
// Phase A: f0..f5  -> cols [0,36),  LDS stride 37 (odd -> 2-way bank alias, free)
// Phase B: f6..f8  -> cols [36,81), LDS stride 45
// Phase C: f9..f10 -> cols [81,121),LDS stride 41

__device__ __forceinline__ float dot3(const float* __restrict__ c, float x, float y, float z) {
    return fmaf(c[2], z, fmaf(c[1], y, c[0] * x));
}

// One order step: out[j] = sum_a prev[a] * (cob[j,3a]*f1x + cob[j,3a+1]*f1y + cob[j,3a+2]*f1z)
// j-loop stays rolled (small I-cache footprint); a-loop unrolled (prev[] must be reg-indexed).
// Results go to the LDS staging row; prev[] is refreshed from there (registers can't be
// dynamically indexed in the rolled j-loop).
template<int LL, bool UPDATE_PREV>
__device__ __forceinline__ void step_l(const float* __restrict__ cob,
                                       float* __restrict__ srow, int colofs,
                                       float f1x, float f1y, float f1z,
                                       float* __restrict__ prev) {
    constexpr int IN  = 2 * LL - 1;
    constexpr int OUT = 2 * LL + 1;
    #pragma unroll 1
    for (int j = 0; j < OUT; ++j) {
        const float* __restrict__ crow = cob + j * (3 * IN);  // wave-uniform -> s_load
        float acc = 0.f;
        #pragma unroll
        for (int a = 0; a < IN; ++a) {
            float s = dot3(crow + 3 * a, f1x, f1y, f1z);
            acc = fmaf(prev[a], s, acc);
        }
        srow[colofs + j] = acc;
    }
    if (UPDATE_PREV) {
        #pragma unroll
        for (int j = 0; j < OUT; ++j) prev[j] = srow[colofs + j];
    }
}

// Coalesced flush of one phase: the block's rows form a contiguous [nvalid x W] slab
// at column CBASE of the [N x 121] output. Consecutive lanes -> consecutive addresses
// (runs of W floats per row).
template<int W, int STRIDE, int CBASE>
__device__ __forceinline__ void flush_phase(const float* __restrict__ sbuf,
                                            float* __restrict__ out,
                                            long long p0, int nvalid, int t) {
    const int total = nvalid * W;
    for (int idx = t; idx < total; idx += BS) {
        const int r = idx / W;          // W is constexpr -> magic-mul
        const int c = idx - r * W;
        out[(p0 + r) * (long long)NFEAT + CBASE + c] = sbuf[r * STRIDE + c];
    }
}

__global__ __launch_bounds__(BS) void harmonic_kernel(
    const float* __restrict__ points,
    const float* __restrict__ cob1,  const float* __restrict__ cob2,
    const float* __restrict__ cob3,  const float* __restrict__ cob4,
    const float* __restrict__ cob5,  const float* __restrict__ cob6,
    const float* __restrict__ cob7,  const float* __restrict__ cob8,
    const float* __restrict__ cob9,  const float* __restrict__ cob10,
    float* __restrict__ out, int N) {
    __shared__ float sbuf[BS * 45];   // 46,080 B -> 3 blocks/CU

    const int t = threadIdx.x;
    const long long p0 = (long long)blockIdx.x * BS;
    const long long p  = p0 + t;
    const bool active = p < (long long)N;
    long long nv = (long long)N - p0;
    const int nvalid = nv > BS ? BS : (int)nv;

    float px = 0.f, py = 0.f, pz = 0.f;
    if (active) {
        px = points[p * 3 + 0];
        py = points[p * 3 + 1];
        pz = points[p * 3 + 2];
    }

    // f1[j] = sum_i points[i] * cob1[j,i]
    const float f1x = dot3(cob1 + 0, px, py, pz);
    const float f1y = dot3(cob1 + 3, px, py, pz);
    const float f1z = dot3(cob1 + 6, px, py, pz);

    float prev[21];
    prev[0] = f1x; prev[1] = f1y; prev[2] = f1z;

    // ---- Phase A: f0..f5, cols [0,36), stride 37 ----
    {
        float* srow = sbuf + t * 37;
        srow[0] = 1.f;
        srow[1] = f1x; srow[2] = f1y; srow[3] = f1z;
        step_l<2, true>(cob2, srow, 4,  f1x, f1y, f1z, prev);   // cols 4..8
        step_l<3, true>(cob3, srow, 9,  f1x, f1y, f1z, prev);   // cols 9..15
        step_l<4, true>(cob4, srow, 16, f1x, f1y, f1z, prev);   // cols 16..24
        step_l<5, true>(cob5, srow, 25, f1x, f1y, f1z, prev);   // cols 25..35
    }
    __syncthreads();
    flush_phase<36, 37, 0>(sbuf, out, p0, nvalid, t);
    __syncthreads();

    // ---- Phase B: f6..f8, cols [36,81), stride 45 ----
    {
        float* srow = sbuf + t * 45;
        step_l<6, true>(cob6, srow, 0,  f1x, f1y, f1z, prev);   // cols 36..48
        step_l<7, true>(cob7, srow, 13, f1x, f1y, f1z, prev);   // cols 49..63
        step_l<8, true>(cob8, srow, 28, f1x, f1y, f1z, prev);   // cols 64..80
    }
    __syncthreads();
    flush_phase<45, 45, 36>(sbuf, out, p0, nvalid, t);
    __syncthreads();

    // ---- Phase C: f9..f10, cols [81,121), stride 41 ----
    {
        float* srow = sbuf + t * 41;
        step_l<9,  true >(cob9,  srow, 0,  f1x, f1y, f1z, prev); // cols 81..99
        step_l<10, false>(cob10, srow, 19, f1x, f1y, f1z, prev); // cols 100..120
    }
    __syncthreads();
    flush_phase<40, 41, 81>(sbuf, out, p0, nvalid, t);
}

extern "C" void kernel_launch(void* const* d_in, const int* in_sizes, int n_in,
                              void* d_out, int out_size, void* d_ws, size_t ws_size,
                              hipStream_t stream) {
    const float* points = (const float*)d_in[0];
    const float* cob[10];
    for (int i = 0; i < 10; ++i) cob[i] = (const float*)d_in[1 + i];
    float* out = (float*)d_out;
    const int N = in_sizes[0] / 3;

    const int grid = (N + BS - 1) / BS;
    harmonic_kernel<<<grid, BS, 0, stream>>>(
        points,
        cob[0], cob[1], cob[2], cob[3], cob[4],
        cob[5], cob[6], cob[7], cob[8], cob[9],
        out, N);
}